// Round 1
// baseline (990.222 us; speedup 1.0000x reference)
//
#include <hip/hip_runtime.h>
#include <hip/hip_bf16.h>

// Problem constants (from reference): N=4096, K=48, P=128, A=5, NBINS=16, RP=32
#define N_RES 4096
#define KNB   48
#define PCH   128

__constant__ float kInvStep = 0.727272727272727f; // 16/22 = 1/1.375

__device__ __forceinline__ void fma4(float4& a, float s, const float4& w) {
  a.x = fmaf(s, w.x, a.x);
  a.y = fmaf(s, w.y, a.y);
  a.z = fmaf(s, w.z, a.z);
  a.w = fmaf(s, w.w, a.w);
}

// jax.nn.gelu approximate=True: 0.5x(1+tanh(sqrt(2/pi)(x+0.044715x^3)))
__device__ __forceinline__ float gelu_t(float x) {
  float u = 0.7978845608028654f * (x + 0.044715f * x * x * x);
  float a = fabsf(u);
  float e = __expf(-2.0f * a);
  float th = (1.0f - e) / (1.0f + e);
  th = (u < 0.0f) ? -th : th;
  return 0.5f * x * (1.0f + th);
}

// p = 15 floats [5 atoms][xyz]; atoms: 0=N, 1=CA, 2=C. R[j*3+i] = e_{i+1}[j]
__device__ __forceinline__ void frame_from_pos(const float* p, float* R) {
  float cax = p[3], cay = p[4], caz = p[5];
  float e1x = p[6]-cax, e1y = p[7]-cay, e1z = p[8]-caz;
  float s1 = e1x*e1x + e1y*e1y + e1z*e1z;
  float i1 = 1.0f / sqrtf(fmaxf(s1, 1e-6f));
  e1x *= i1; e1y *= i1; e1z *= i1;
  float vx = p[0]-cax, vy = p[1]-cay, vz = p[2]-caz;
  float dp = vx*e1x + vy*e1y + vz*e1z;
  float e2x = vx - dp*e1x, e2y = vy - dp*e1y, e2z = vz - dp*e1z;
  float s2 = e2x*e2x + e2y*e2y + e2z*e2z;
  float i2 = 1.0f / sqrtf(fmaxf(s2, 1e-6f));
  e2x *= i2; e2y *= i2; e2z *= i2;
  float e3x = e1y*e2z - e1z*e2y;
  float e3y = e1z*e2x - e1x*e2z;
  float e3z = e1x*e2y - e1y*e2x;
  R[0]=e1x; R[1]=e2x; R[2]=e3x;
  R[3]=e1y; R[4]=e2y; R[5]=e3y;
  R[6]=e1z; R[7]=e2z; R[8]=e3z;
}

// One block per residue n; 256 threads.
__global__ __launch_bounds__(256) void fused_struct_kernel(
    const float* __restrict__ pos, const float* __restrict__ dmap,
    const float* __restrict__ mask, const float* __restrict__ W_relpos,
    const float* __restrict__ W_dmap, const float* __restrict__ W_dist,
    const float* __restrict__ W_dir, const float* __restrict__ W_rot,
    const float* __restrict__ W_vec, const float* __restrict__ ln_scale,
    const float* __restrict__ ln_offset, const float* __restrict__ W1,
    const float* __restrict__ b1, const float* __restrict__ W2,
    const float* __restrict__ b2, const int* __restrict__ neighbours,
    const int* __restrict__ resi, const int* __restrict__ chain,
    const int* __restrict__ batch, float* __restrict__ out)
{
  const int n = blockIdx.x;
  const int t = threadIdx.x;

  // LDS: ~49.8 KB total -> 3 blocks/CU on 160 KB LDS, under 64 KB static limit
  __shared__ float s_pair[48*132];   // post-LN pair, padded stride 132 (bank-conflict-free)
  __shared__ float s_mix[6000];      // phase1: posnb|Rnb|small|x|rbf ; phase2: h-tile
  __shared__ float s_posn[16];
  __shared__ float s_Rn[12];
  __shared__ int   s_cls[48];

  float* s_posnb = s_mix;            // [48][16] (15 used)
  float* s_Rnb   = s_mix + 768;      // [48][12] (9 used)
  float* s_small = s_mix + 1344;     // [48][56]: 0..15 dmap-rbf | 16..30 dir | 31..45 vec | 46..54 rot
  float* s_x     = s_mix + 4032;     // [25][48] scaled distances d/step
  float* s_rbf   = s_mix + 5232;     // [48][16] current chunk
  float* s_ht    = s_mix;            // [48][68] hidden tile (aliased, phase 5)

  // ---------------- phase 1: neighbour loads, frames, mask, cls, dmap rbf ----
  if (t < KNB) {
    const int k = t;
    const int nbraw = neighbours[n*KNB + k];
    int nb = nbraw; if (nb < 0) nb += N_RES;   // JAX negative-index wrap
    float p[15];
    const float* pp = pos + nb*15;
    #pragma unroll
    for (int d = 0; d < 15; ++d) { p[d] = pp[d]; s_posnb[k*16+d] = p[d]; }
    float R[9];
    frame_from_pos(p, R);
    #pragma unroll
    for (int d = 0; d < 9; ++d) s_Rnb[k*12+d] = R[d];

    float pm = mask[n] * mask[nb] * ((nbraw != -1) ? 1.0f : 0.0f);
    out[N_RES*KNB*PCH + n*KNB + k] = pm;       // pair_mask output

    int rel = resi[nb] - resi[n];
    rel = (rel < -32) ? -32 : (rel > 32 ? 32 : rel);
    rel += 32;
    bool same = (chain[nb] == chain[n]) && (batch[nb] == batch[n]);
    s_cls[k] = same ? rel : 65;

    float xd = dmap[(long long)n*N_RES + nb] * kInvStep;
    #pragma unroll
    for (int b = 0; b < 16; ++b) {
      float df = xd - (float)b;
      s_small[k*56 + b] = (pm > 0.0f) ? __expf(-df*df) : 0.0f;
    }
  } else if (t == 255) {
    float p[15];
    const float* pp = pos + n*15;
    #pragma unroll
    for (int d = 0; d < 15; ++d) { p[d] = pp[d]; s_posn[d] = p[d]; }
    float R[9];
    frame_from_pos(p, R);
    #pragma unroll
    for (int d = 0; d < 9; ++d) s_Rn[d] = R[d];
  }
  __syncthreads();

  // ---------------- phase 2: dir/vec, rot, all scaled distances ----
  // dir + vec: 48*5 = 240 (local = R^T (pos[nb,a]-ca))
  for (int idx = t; idx < 240; idx += 256) {
    int k = idx / 5, a = idx - 5*k;
    float rx = s_posnb[k*16 + a*3+0] - s_posn[3];
    float ry = s_posnb[k*16 + a*3+1] - s_posn[4];
    float rz = s_posnb[k*16 + a*3+2] - s_posn[5];
    float l0 = s_Rn[0]*rx + s_Rn[3]*ry + s_Rn[6]*rz;
    float l1 = s_Rn[1]*rx + s_Rn[4]*ry + s_Rn[7]*rz;
    float l2 = s_Rn[2]*rx + s_Rn[5]*ry + s_Rn[8]*rz;
    s_small[k*56 + 31 + a*3+0] = l0;
    s_small[k*56 + 31 + a*3+1] = l1;
    s_small[k*56 + 31 + a*3+2] = l2;
    float n2 = l0*l0 + l1*l1 + l2*l2;
    float inv = 1.0f / sqrtf(fmaxf(n2, 1e-6f));
    s_small[k*56 + 16 + a*3+0] = l0*inv;
    s_small[k*56 + 16 + a*3+1] = l1*inv;
    s_small[k*56 + 16 + a*3+2] = l2*inv;
  }
  // rot: Rrel[i][l] = sum_j Rn[j][i]*Rnb[j][l], 48*9 = 432
  for (int idx = t; idx < 432; idx += 256) {
    int k = idx / 9, il = idx - 9*k;
    int i = il / 3, l = il - 3*i;
    float v = s_Rn[0+i]*s_Rnb[k*12 + 0+l]
            + s_Rn[3+i]*s_Rnb[k*12 + 3+l]
            + s_Rn[6+i]*s_Rnb[k*12 + 6+l];
    s_small[k*56 + 46 + il] = v;
  }
  // distances: 25*48 = 1200, x = d/step
  for (int idx = t; idx < 1200; idx += 256) {
    int c = idx / 48, k = idx - 48*c;
    int a1 = c / 5, a2 = c - 5*a1;
    float dx = s_posn[a1*3+0] - s_posnb[k*16 + a2*3+0];
    float dy = s_posn[a1*3+1] - s_posnb[k*16 + a2*3+1];
    float dz = s_posn[a1*3+2] - s_posnb[k*16 + a2*3+2];
    float d2 = dx*dx + dy*dy + dz*dz;
    s_x[c*48 + k] = sqrtf(fmaxf(d2, 1e-12f)) * kInvStep;
  }

  // ---------------- phase 3: accumulate pair (pre-LN) ----
  const int c4 = t & 31;   // channel quad: columns 4*c4 .. 4*c4+3
  const int kg = t >> 5;   // [0,8): k = kg*6 + j
  float4 acc[6];
  #pragma unroll
  for (int j = 0; j < 6; ++j) {
    int cls = s_cls[kg*6 + j];
    acc[j] = *(const float4*)(W_relpos + cls*PCH + 4*c4);
  }
  __syncthreads();  // s_small fully built

  // small features (dmap 16 | dir 15 | vec 15 | rot 9)
  for (int f = 0; f < 55; ++f) {
    const float* Wf = (f < 16) ? (W_dmap + f*PCH)
                    : (f < 31) ? (W_dir + (f-16)*PCH)
                    : (f < 46) ? (W_vec + (f-31)*PCH)
                               : (W_rot + (f-46)*PCH);
    float4 w = *(const float4*)(Wf + 4*c4);
    #pragma unroll
    for (int j = 0; j < 6; ++j) {
      fma4(acc[j], s_small[(kg*6+j)*56 + f], w);
    }
  }

  // distance RBF chunks: 25 x (16 bins)
  for (int c = 0; c < 25; ++c) {
    __syncthreads();   // previous accumulate done before s_rbf overwrite
    for (int idx = t; idx < 768; idx += 256) {
      int k = idx >> 4, b = idx & 15;
      float df = s_x[c*48 + k] - (float)b;
      s_rbf[idx] = __expf(-df*df);
    }
    __syncthreads();
    const float* Wc = W_dist + c*(16*PCH);
    #pragma unroll
    for (int bq = 0; bq < 4; ++bq) {
      float4 w0 = *(const float4*)(Wc + (bq*4+0)*PCH + 4*c4);
      float4 w1 = *(const float4*)(Wc + (bq*4+1)*PCH + 4*c4);
      float4 w2 = *(const float4*)(Wc + (bq*4+2)*PCH + 4*c4);
      float4 w3 = *(const float4*)(Wc + (bq*4+3)*PCH + 4*c4);
      #pragma unroll
      for (int j = 0; j < 6; ++j) {
        float4 r = *(const float4*)&s_rbf[(kg*6+j)*16 + bq*4];
        fma4(acc[j], r.x, w0);
        fma4(acc[j], r.y, w1);
        fma4(acc[j], r.z, w2);
        fma4(acc[j], r.w, w3);
      }
    }
  }

  // ---------------- phase 4: LayerNorm over P=128 -> s_pair ----
  {
    float4 g  = *(const float4*)(ln_scale  + 4*c4);
    float4 o4 = *(const float4*)(ln_offset + 4*c4);
    #pragma unroll
    for (int j = 0; j < 6; ++j) {
      float s = acc[j].x + acc[j].y + acc[j].z + acc[j].w;
      float q = acc[j].x*acc[j].x + acc[j].y*acc[j].y
              + acc[j].z*acc[j].z + acc[j].w*acc[j].w;
      #pragma unroll
      for (int m = 1; m < 32; m <<= 1) {
        s += __shfl_xor(s, m);
        q += __shfl_xor(q, m);
      }
      float mu  = s * (1.0f/128.0f);
      float var = q * (1.0f/128.0f) - mu*mu;
      float inv = 1.0f / sqrtf(var + 1e-5f);
      float4 v;
      v.x = (acc[j].x - mu)*inv*g.x + o4.x;
      v.y = (acc[j].y - mu)*inv*g.y + o4.y;
      v.z = (acc[j].z - mu)*inv*g.z + o4.z;
      v.w = (acc[j].w - mu)*inv*g.w + o4.w;
      *(float4*)&s_pair[(kg*6+j)*132 + 4*c4] = v;
    }
  }
  __syncthreads();   // s_pair ready; s_mix (s_ht alias) free

  // ---------------- phase 5: MLP in 4 hidden tiles of 64 ----
  const int jl  = t & 15;   // hidden col quad within tile
  const int kg3 = t >> 4;   // [0,16): k = kg3*3 + j
  float4 o[6];
  #pragma unroll
  for (int j = 0; j < 6; ++j) o[j] = *(const float4*)(b2 + 4*c4);

  for (int jt = 0; jt < 4; ++jt) {
    // ---- h-tile = pair @ W1[:, jt*64 : jt*64+64] + b1
    float4 h[3];
    #pragma unroll
    for (int j = 0; j < 3; ++j) h[j] = *(const float4*)(b1 + jt*64 + 4*jl);
    for (int fq = 0; fq < 32; ++fq) {
      const float* Wb = W1 + 4*fq*256 + jt*64 + 4*jl;
      float4 w0 = *(const float4*)(Wb);
      float4 w1 = *(const float4*)(Wb + 256);
      float4 w2 = *(const float4*)(Wb + 512);
      float4 w3 = *(const float4*)(Wb + 768);
      #pragma unroll
      for (int j = 0; j < 3; ++j) {
        float4 pv = *(const float4*)&s_pair[(kg3*3+j)*132 + 4*fq];
        fma4(h[j], pv.x, w0);
        fma4(h[j], pv.y, w1);
        fma4(h[j], pv.z, w2);
        fma4(h[j], pv.w, w3);
      }
    }
    #pragma unroll
    for (int j = 0; j < 3; ++j) {
      float4 hg;
      hg.x = gelu_t(h[j].x); hg.y = gelu_t(h[j].y);
      hg.z = gelu_t(h[j].z); hg.w = gelu_t(h[j].w);
      *(float4*)&s_ht[(kg3*3+j)*68 + 4*jl] = hg;
    }
    __syncthreads();
    // ---- out += gelu(h-tile) @ W2[jt*64 : jt*64+64, :]
    for (int jq = 0; jq < 16; ++jq) {
      const float* Wb = W2 + (jt*64 + 4*jq)*PCH + 4*c4;
      float4 w0 = *(const float4*)(Wb);
      float4 w1 = *(const float4*)(Wb + PCH);
      float4 w2 = *(const float4*)(Wb + 2*PCH);
      float4 w3 = *(const float4*)(Wb + 3*PCH);
      #pragma unroll
      for (int j = 0; j < 6; ++j) {
        float4 hv = *(const float4*)&s_ht[(kg*6+j)*68 + 4*jq];
        fma4(o[j], hv.x, w0);
        fma4(o[j], hv.y, w1);
        fma4(o[j], hv.z, w2);
        fma4(o[j], hv.w, w3);
      }
    }
    __syncthreads();   // protect s_ht before next tile overwrite
  }

  // ---------------- phase 6: write pair output ----
  #pragma unroll
  for (int j = 0; j < 6; ++j) {
    int k = kg*6 + j;
    *(float4*)(out + (n*KNB + k)*PCH + 4*c4) = o[j];
  }
}

extern "C" void kernel_launch(void* const* d_in, const int* in_sizes, int n_in,
                              void* d_out, int out_size, void* d_ws, size_t ws_size,
                              hipStream_t stream) {
  const float* pos       = (const float*)d_in[0];
  const float* dmap      = (const float*)d_in[1];
  const float* mask      = (const float*)d_in[2];
  const float* W_relpos  = (const float*)d_in[3];
  const float* W_dmap    = (const float*)d_in[4];
  const float* W_dist    = (const float*)d_in[5];
  const float* W_dir     = (const float*)d_in[6];
  const float* W_rot     = (const float*)d_in[7];
  const float* W_vec     = (const float*)d_in[8];
  const float* ln_scale  = (const float*)d_in[9];
  const float* ln_offset = (const float*)d_in[10];
  const float* W1        = (const float*)d_in[11];
  const float* b1        = (const float*)d_in[12];
  const float* W2        = (const float*)d_in[13];
  const float* b2        = (const float*)d_in[14];
  const int* neighbours  = (const int*)d_in[15];
  const int* resi        = (const int*)d_in[16];
  const int* chain       = (const int*)d_in[17];
  const int* batch       = (const int*)d_in[18];
  float* out = (float*)d_out;

  hipLaunchKernelGGL(fused_struct_kernel, dim3(N_RES), dim3(256), 0, stream,
                     pos, dmap, mask, W_relpos, W_dmap, W_dist, W_dir, W_rot,
                     W_vec, ln_scale, ln_offset, W1, b1, W2, b2,
                     neighbours, resi, chain, batch, out);
}

// Round 2
// 380.847 us; speedup vs baseline: 2.6001x; 2.6001x over previous
//
#include <hip/hip_runtime.h>
#include <hip/hip_bf16.h>

// N=4096, K=48, P=128, A=5, NBINS=16, RP=32
#define N_RES 4096
#define KNB   48
#define PCH   128

typedef __bf16 bf16x8 __attribute__((ext_vector_type(8)));
typedef float  f32x4  __attribute__((ext_vector_type(4)));

__device__ __forceinline__ unsigned short f2bf(float f) {
  unsigned int u = __float_as_uint(f);
  return (unsigned short)((u + 0x7fffu + ((u >> 16) & 1u)) >> 16);
}

// jax.nn.gelu approximate=True
__device__ __forceinline__ float gelu_t(float x) {
  float u = 0.7978845608028654f * (x + 0.044715f * x * x * x);
  float a = fabsf(u);
  float e = __expf(-2.0f * a);
  float th = (1.0f - e) / (1.0f + e);
  th = (u < 0.0f) ? -th : th;
  return 0.5f * x * (1.0f + th);
}

__device__ __forceinline__ void frame_from_pos(const float* p, float* R) {
  float cax = p[3], cay = p[4], caz = p[5];
  float e1x = p[6]-cax, e1y = p[7]-cay, e1z = p[8]-caz;
  float s1 = e1x*e1x + e1y*e1y + e1z*e1z;
  float i1 = 1.0f / sqrtf(fmaxf(s1, 1e-6f));
  e1x *= i1; e1y *= i1; e1z *= i1;
  float vx = p[0]-cax, vy = p[1]-cay, vz = p[2]-caz;
  float dp = vx*e1x + vy*e1y + vz*e1z;
  float e2x = vx - dp*e1x, e2y = vy - dp*e1y, e2z = vz - dp*e1z;
  float s2 = e2x*e2x + e2y*e2y + e2z*e2z;
  float i2 = 1.0f / sqrtf(fmaxf(s2, 1e-6f));
  e2x *= i2; e2y *= i2; e2z *= i2;
  float e3x = e1y*e2z - e1z*e2y;
  float e3y = e1z*e2x - e1x*e2z;
  float e3z = e1x*e2y - e1y*e2x;
  R[0]=e1x; R[1]=e2x; R[2]=e3x;
  R[3]=e1y; R[4]=e2y; R[5]=e3y;
  R[6]=e1z; R[7]=e2z; R[8]=e3z;
}

// ---- prep: build bf16 transposed weight matrices in ws ----
// ws (ushort): [0,65536) WcatT[128][512]; [65536,98304) W1T[256][128];
//              [98304,131072) W2T[128][256]
__global__ __launch_bounds__(256) void prep_weights(
    const float* __restrict__ W_dmap, const float* __restrict__ W_dist,
    const float* __restrict__ W_dir, const float* __restrict__ W_vec,
    const float* __restrict__ W_rot, const float* __restrict__ W1,
    const float* __restrict__ W2, unsigned short* __restrict__ ws)
{
  int i = blockIdx.x * 256 + threadIdx.x;
  if (i < 65536) {                       // WcatT[n][k], k in [0,512)
    int n = i >> 9, k = i & 511;
    float v = 0.0f;
    if      (k < 16)  v = W_dmap[k*PCH + n];
    else if (k < 416) v = W_dist[(k-16)*PCH + n];
    else if (k < 431) v = W_dir[(k-416)*PCH + n];
    else if (k < 446) v = W_vec[(k-431)*PCH + n];
    else if (k < 455) v = W_rot[(k-446)*PCH + n];
    ws[i] = f2bf(v);
  } else if (i < 98304) {                // W1T[n][k]: W1 is [128][256]
    int j = i - 65536; int n = j >> 7, k = j & 127;
    ws[i] = f2bf(W1[k*256 + n]);
  } else if (i < 131072) {               // W2T[n][k]: W2 is [256][128]
    int j = i - 98304; int n = j >> 8, k = j & 255;
    ws[i] = f2bf(W2[k*PCH + n]);
  }
}

// ---- main: one block per residue, 256 threads (4 waves) ----
__global__ __launch_bounds__(256) void fused_struct_kernel(
    const float* __restrict__ pos, const float* __restrict__ dmap,
    const float* __restrict__ mask, const float* __restrict__ W_relpos,
    const float* __restrict__ ln_scale, const float* __restrict__ ln_offset,
    const float* __restrict__ b1, const float* __restrict__ b2,
    const int* __restrict__ neighbours, const int* __restrict__ resi,
    const int* __restrict__ chain, const int* __restrict__ batch,
    const unsigned short* __restrict__ wsw, float* __restrict__ out)
{
  const int n = blockIdx.x;
  const int t = threadIdx.x;

  // region1: F[48][488] bf16 (46848 B)  ALIASED WITH  C[48][132] f32 (25344 B)
  //          ALIASED WITH h[48][264] bf16 (25344 B)
  __shared__ __align__(16) char reg1[48*488*2];
  // region2: pairb[48][136] bf16 (13056 B) ALIASED WITH feature scratch
  __shared__ __align__(16) char reg2[48*136*2];
  __shared__ int s_cls[48];

  unsigned short* s_F     = (unsigned short*)reg1;
  float*          s_C     = (float*)reg1;
  unsigned short* s_hb    = (unsigned short*)reg1;
  unsigned short* s_pairb = (unsigned short*)reg2;
  float* s_posnb = (float*)reg2;             // [48][16]
  float* s_Rnb   = (float*)(reg2 + 3072);    // [48][12]
  float* s_x     = (float*)(reg2 + 5376);    // [25][48]
  float* s_posn  = (float*)(reg2 + 10176);   // 16
  float* s_Rn    = (float*)(reg2 + 10240);   // 12

  const unsigned short* wcatT = wsw;
  const unsigned short* w1T   = wsw + 65536;
  const unsigned short* w2T   = wsw + 98304;

  // ---------------- phase 1 ----------------
  if (t < KNB) {
    const int k = t;
    const int nbraw = neighbours[n*KNB + k];
    int nb = nbraw; if (nb < 0) nb += N_RES;
    float p[15];
    const float* pp = pos + nb*15;
    #pragma unroll
    for (int d = 0; d < 15; ++d) { p[d] = pp[d]; s_posnb[k*16+d] = p[d]; }
    float R[9];
    frame_from_pos(p, R);
    #pragma unroll
    for (int d = 0; d < 9; ++d) s_Rnb[k*12+d] = R[d];

    float pm = mask[n] * mask[nb] * ((nbraw != -1) ? 1.0f : 0.0f);
    out[N_RES*KNB*PCH + n*KNB + k] = pm;

    int rel = resi[nb] - resi[n];
    rel = (rel < -32) ? -32 : (rel > 32 ? 32 : rel);
    rel += 32;
    bool same = (chain[nb] == chain[n]) && (batch[nb] == batch[n]);
    s_cls[k] = same ? rel : 65;

    float xd = dmap[(long long)n*N_RES + nb] * 0.727272727272727f;
    #pragma unroll
    for (int b = 0; b < 16; ++b) {
      float df = xd - (float)b;
      s_F[k*488 + b] = (pm > 0.0f) ? f2bf(__expf(-df*df)) : (unsigned short)0;
    }
  } else if (t == 255) {
    float p[15];
    const float* pp = pos + n*15;
    #pragma unroll
    for (int d = 0; d < 15; ++d) { p[d] = pp[d]; s_posn[d] = p[d]; }
    float R[9];
    frame_from_pos(p, R);
    #pragma unroll
    for (int d = 0; d < 9; ++d) s_Rn[d] = R[d];
  }
  __syncthreads();

  // ---------------- phase 2a: dir/vec/rot + distances ----------------
  for (int idx = t; idx < 240; idx += 256) {
    int k = idx / 5, a = idx - 5*k;
    float rx = s_posnb[k*16 + a*3+0] - s_posn[3];
    float ry = s_posnb[k*16 + a*3+1] - s_posn[4];
    float rz = s_posnb[k*16 + a*3+2] - s_posn[5];
    float l0 = s_Rn[0]*rx + s_Rn[3]*ry + s_Rn[6]*rz;
    float l1 = s_Rn[1]*rx + s_Rn[4]*ry + s_Rn[7]*rz;
    float l2 = s_Rn[2]*rx + s_Rn[5]*ry + s_Rn[8]*rz;
    s_F[k*488 + 431 + a*3+0] = f2bf(l0);       // vec
    s_F[k*488 + 431 + a*3+1] = f2bf(l1);
    s_F[k*488 + 431 + a*3+2] = f2bf(l2);
    float n2 = l0*l0 + l1*l1 + l2*l2;
    float inv = 1.0f / sqrtf(fmaxf(n2, 1e-6f));
    s_F[k*488 + 416 + a*3+0] = f2bf(l0*inv);   // dir
    s_F[k*488 + 416 + a*3+1] = f2bf(l1*inv);
    s_F[k*488 + 416 + a*3+2] = f2bf(l2*inv);
  }
  for (int idx = t; idx < 432; idx += 256) {   // rot
    int k = idx / 9, il = idx - 9*k;
    int i = il / 3, l = il - 3*i;
    float v = s_Rn[0+i]*s_Rnb[k*12 + 0+l]
            + s_Rn[3+i]*s_Rnb[k*12 + 3+l]
            + s_Rn[6+i]*s_Rnb[k*12 + 6+l];
    s_F[k*488 + 446 + il] = f2bf(v);
  }
  for (int idx = t; idx < 1200; idx += 256) {  // scaled distances
    int c = idx / 48, k = idx - 48*c;
    int a1 = c / 5, a2 = c - 5*a1;
    float dx = s_posn[a1*3+0] - s_posnb[k*16 + a2*3+0];
    float dy = s_posn[a1*3+1] - s_posnb[k*16 + a2*3+1];
    float dz = s_posn[a1*3+2] - s_posnb[k*16 + a2*3+2];
    float d2 = dx*dx + dy*dy + dz*dz;
    s_x[c*48 + k] = sqrtf(fmaxf(d2, 1e-12f)) * 0.727272727272727f;
  }
  __syncthreads();

  // ---------------- phase 2b: distance RBF + zero pad ----------------
  for (int idx = t; idx < 19200; idx += 256) {
    int m = idx / 400, f = idx - 400*m;
    int c = f >> 4;
    float df = s_x[c*48 + m] - (float)(f & 15);
    s_F[m*488 + 16 + f] = f2bf(__expf(-df*df));
  }
  for (int idx = t; idx < 1200; idx += 256) {
    int m = idx / 25, f = idx - 25*m;
    s_F[m*488 + 455 + f] = 0;
  }
  __syncthreads();

  // ---------------- GEMM1: C[48][128] = F[48][480] @ Wcat ----------------
  const int lane = t & 63;
  const int wv   = t >> 6;          // wave id: cols 32*wv .. 32*wv+31
  const int ln15 = lane & 15;
  const int quad = lane >> 4;

  f32x4 acc1[3][2] = {};
  #pragma unroll
  for (int kc = 0; kc < 15; ++kc) {
    bf16x8 a0 = *(const bf16x8*)(s_F + ( 0 + ln15)*488 + kc*32 + quad*8);
    bf16x8 a1 = *(const bf16x8*)(s_F + (16 + ln15)*488 + kc*32 + quad*8);
    bf16x8 a2 = *(const bf16x8*)(s_F + (32 + ln15)*488 + kc*32 + quad*8);
    bf16x8 b0 = *(const bf16x8*)(wcatT + (32*wv      + ln15)*512 + kc*32 + quad*8);
    bf16x8 b1v= *(const bf16x8*)(wcatT + (32*wv + 16 + ln15)*512 + kc*32 + quad*8);
    acc1[0][0] = __builtin_amdgcn_mfma_f32_16x16x32_bf16(a0, b0,  acc1[0][0], 0,0,0);
    acc1[1][0] = __builtin_amdgcn_mfma_f32_16x16x32_bf16(a1, b0,  acc1[1][0], 0,0,0);
    acc1[2][0] = __builtin_amdgcn_mfma_f32_16x16x32_bf16(a2, b0,  acc1[2][0], 0,0,0);
    acc1[0][1] = __builtin_amdgcn_mfma_f32_16x16x32_bf16(a0, b1v, acc1[0][1], 0,0,0);
    acc1[1][1] = __builtin_amdgcn_mfma_f32_16x16x32_bf16(a1, b1v, acc1[1][1], 0,0,0);
    acc1[2][1] = __builtin_amdgcn_mfma_f32_16x16x32_bf16(a2, b1v, acc1[2][1], 0,0,0);
  }
  __syncthreads();                  // all F reads done; region1 -> C

  #pragma unroll
  for (int mt = 0; mt < 3; ++mt)
    #pragma unroll
    for (int nt = 0; nt < 2; ++nt) {
      int col = 32*wv + nt*16 + ln15;
      #pragma unroll
      for (int r = 0; r < 4; ++r)
        s_C[(mt*16 + quad*4 + r)*132 + col] = acc1[mt][nt][r];
    }
  __syncthreads();

  // ---------------- LN (+relpos gather) -> pairb bf16 ----------------
  {
    const int c4 = t & 31;    // channel quad
    const int kg = t >> 5;    // row group: rows kg*6 .. kg*6+5
    float4 g  = *(const float4*)(ln_scale  + 4*c4);
    float4 o4 = *(const float4*)(ln_offset + 4*c4);
    #pragma unroll
    for (int j = 0; j < 6; ++j) {
      int k = kg*6 + j;
      float4 v = *(const float4*)&s_C[k*132 + 4*c4];
      float4 w = *(const float4*)(W_relpos + s_cls[k]*PCH + 4*c4);
      v.x += w.x; v.y += w.y; v.z += w.z; v.w += w.w;
      float s = v.x + v.y + v.z + v.w;
      float q = v.x*v.x + v.y*v.y + v.z*v.z + v.w*v.w;
      #pragma unroll
      for (int m = 1; m < 32; m <<= 1) {
        s += __shfl_xor(s, m);
        q += __shfl_xor(q, m);
      }
      float mu  = s * (1.0f/128.0f);
      float var = q * (1.0f/128.0f) - mu*mu;
      float inv = 1.0f / sqrtf(var + 1e-5f);
      unsigned short b0 = f2bf((v.x - mu)*inv*g.x + o4.x);
      unsigned short b1s= f2bf((v.y - mu)*inv*g.y + o4.y);
      unsigned short b2s= f2bf((v.z - mu)*inv*g.z + o4.z);
      unsigned short b3 = f2bf((v.w - mu)*inv*g.w + o4.w);
      unsigned int lo = (unsigned int)b0 | ((unsigned int)b1s << 16);
      unsigned int hi = (unsigned int)b2s | ((unsigned int)b3 << 16);
      *(uint2*)&s_pairb[k*136 + 4*c4] = make_uint2(lo, hi);
    }
  }
  __syncthreads();

  // ---------------- GEMM2: H[48][256] = pair @ W1, gelu -> hb ----------------
  f32x4 acc2[3][4] = {};
  #pragma unroll
  for (int kc = 0; kc < 4; ++kc) {
    bf16x8 a[3];
    #pragma unroll
    for (int mt = 0; mt < 3; ++mt)
      a[mt] = *(const bf16x8*)(s_pairb + (mt*16 + ln15)*136 + kc*32 + quad*8);
    bf16x8 b[4];
    #pragma unroll
    for (int nt = 0; nt < 4; ++nt)
      b[nt] = *(const bf16x8*)(w1T + (64*wv + nt*16 + ln15)*128 + kc*32 + quad*8);
    #pragma unroll
    for (int mt = 0; mt < 3; ++mt)
      #pragma unroll
      for (int nt = 0; nt < 4; ++nt)
        acc2[mt][nt] = __builtin_amdgcn_mfma_f32_16x16x32_bf16(a[mt], b[nt], acc2[mt][nt], 0,0,0);
  }
  #pragma unroll
  for (int nt = 0; nt < 4; ++nt) {
    int col = 64*wv + nt*16 + ln15;
    float bias = b1[col];
    #pragma unroll
    for (int mt = 0; mt < 3; ++mt)
      #pragma unroll
      for (int r = 0; r < 4; ++r)
        s_hb[(mt*16 + quad*4 + r)*264 + col] = f2bf(gelu_t(acc2[mt][nt][r] + bias));
  }
  __syncthreads();

  // ---------------- GEMM3: O[48][128] = hb @ W2 + b2 -> out ----------------
  f32x4 acc3[3][2] = {};
  #pragma unroll
  for (int kc = 0; kc < 8; ++kc) {
    bf16x8 a[3];
    #pragma unroll
    for (int mt = 0; mt < 3; ++mt)
      a[mt] = *(const bf16x8*)(s_hb + (mt*16 + ln15)*264 + kc*32 + quad*8);
    bf16x8 b0 = *(const bf16x8*)(w2T + (32*wv      + ln15)*256 + kc*32 + quad*8);
    bf16x8 b1v= *(const bf16x8*)(w2T + (32*wv + 16 + ln15)*256 + kc*32 + quad*8);
    #pragma unroll
    for (int mt = 0; mt < 3; ++mt) {
      acc3[mt][0] = __builtin_amdgcn_mfma_f32_16x16x32_bf16(a[mt], b0,  acc3[mt][0], 0,0,0);
      acc3[mt][1] = __builtin_amdgcn_mfma_f32_16x16x32_bf16(a[mt], b1v, acc3[mt][1], 0,0,0);
    }
  }
  #pragma unroll
  for (int nt = 0; nt < 2; ++nt) {
    int col = 32*wv + nt*16 + ln15;
    float bias = b2[col];
    #pragma unroll
    for (int mt = 0; mt < 3; ++mt)
      #pragma unroll
      for (int r = 0; r < 4; ++r)
        out[(n*KNB + mt*16 + quad*4 + r)*PCH + col] = acc3[mt][nt][r] + bias;
  }
}

extern "C" void kernel_launch(void* const* d_in, const int* in_sizes, int n_in,
                              void* d_out, int out_size, void* d_ws, size_t ws_size,
                              hipStream_t stream) {
  const float* pos       = (const float*)d_in[0];
  const float* dmap      = (const float*)d_in[1];
  const float* mask      = (const float*)d_in[2];
  const float* W_relpos  = (const float*)d_in[3];
  const float* W_dmap    = (const float*)d_in[4];
  const float* W_dist    = (const float*)d_in[5];
  const float* W_dir     = (const float*)d_in[6];
  const float* W_rot     = (const float*)d_in[7];
  const float* W_vec     = (const float*)d_in[8];
  const float* ln_scale  = (const float*)d_in[9];
  const float* ln_offset = (const float*)d_in[10];
  const float* W1        = (const float*)d_in[11];
  const float* b1        = (const float*)d_in[12];
  const float* W2        = (const float*)d_in[13];
  const float* b2        = (const float*)d_in[14];
  const int* neighbours  = (const int*)d_in[15];
  const int* resi        = (const int*)d_in[16];
  const int* chain       = (const int*)d_in[17];
  const int* batch       = (const int*)d_in[18];
  float* out = (float*)d_out;
  unsigned short* wsw = (unsigned short*)d_ws;

  hipLaunchKernelGGL(prep_weights, dim3(512), dim3(256), 0, stream,
                     W_dmap, W_dist, W_dir, W_vec, W_rot, W1, W2, wsw);
  hipLaunchKernelGGL(fused_struct_kernel, dim3(N_RES), dim3(256), 0, stream,
                     pos, dmap, mask, W_relpos, ln_scale, ln_offset, b1, b2,
                     neighbours, resi, chain, batch, wsw, out);
}

// Round 3
// 332.917 us; speedup vs baseline: 2.9744x; 1.1440x over previous
//
#include <hip/hip_runtime.h>
#include <hip/hip_bf16.h>

// N=4096, K=48, P=128, A=5, NBINS=16, RP=32
#define N_RES 4096
#define KNB   48
#define PCH   128
#define FSTR  264                 // F/hb row stride (elems): 528 B = 33*16 -> conflict-light b128
#define INV_STEP 0.727272727272727f

typedef __bf16 bf16x8 __attribute__((ext_vector_type(8)));
typedef float  f32x4  __attribute__((ext_vector_type(4)));

__device__ __forceinline__ unsigned short f2bf(float f) {
  unsigned int u = __float_as_uint(f);
  return (unsigned short)((u + 0x7fffu + ((u >> 16) & 1u)) >> 16);
}

__device__ __forceinline__ unsigned int pk2(float a, float b) {
  __hip_bfloat162 h = __float22bfloat162_rn(make_float2(a, b));  // v_cvt_pk_bf16_f32
  unsigned int u;
  __builtin_memcpy(&u, &h, 4);
  return u;
}

// jax.nn.gelu approximate=True
__device__ __forceinline__ float gelu_t(float x) {
  float u = 0.7978845608028654f * (x + 0.044715f * x * x * x);
  float a = fabsf(u);
  float e = __expf(-2.0f * a);
  float th = (1.0f - e) / (1.0f + e);
  th = (u < 0.0f) ? -th : th;
  return 0.5f * x * (1.0f + th);
}

__device__ __forceinline__ void frame_from_pos(const float* p, float* R) {
  float cax = p[3], cay = p[4], caz = p[5];
  float e1x = p[6]-cax, e1y = p[7]-cay, e1z = p[8]-caz;
  float s1 = e1x*e1x + e1y*e1y + e1z*e1z;
  float i1 = 1.0f / sqrtf(fmaxf(s1, 1e-6f));
  e1x *= i1; e1y *= i1; e1z *= i1;
  float vx = p[0]-cax, vy = p[1]-cay, vz = p[2]-caz;
  float dp = vx*e1x + vy*e1y + vz*e1z;
  float e2x = vx - dp*e1x, e2y = vy - dp*e1y, e2z = vz - dp*e1z;
  float s2 = e2x*e2x + e2y*e2y + e2z*e2z;
  float i2 = 1.0f / sqrtf(fmaxf(s2, 1e-6f));
  e2x *= i2; e2y *= i2; e2z *= i2;
  float e3x = e1y*e2z - e1z*e2y;
  float e3y = e1z*e2x - e1x*e2z;
  float e3z = e1x*e2y - e1y*e2x;
  R[0]=e1x; R[1]=e2x; R[2]=e3x;
  R[3]=e1y; R[4]=e2y; R[5]=e3y;
  R[6]=e1z; R[7]=e2z; R[8]=e3z;
}

// ---- prep: bf16 transposed weights in ws, COALESCED reads ----
// ws (ushort): [0,65536) WcatT[128][512] (k: 0..15 dmap | 16..415 dist | 416 dir |
//              431 vec | 446 rot | 455..511 zero); [65536,98304) W1T[256][128];
//              [98304,131072) W2T[128][256]
__global__ __launch_bounds__(256) void prep_weights(
    const float* __restrict__ W_dmap, const float* __restrict__ W_dist,
    const float* __restrict__ W_dir, const float* __restrict__ W_vec,
    const float* __restrict__ W_rot, const float* __restrict__ W1,
    const float* __restrict__ W2, unsigned short* __restrict__ ws)
{
  int i = blockIdx.x * 256 + threadIdx.x;
  if (i < 51200) {                       // W_dist [400][128]
    int r = i >> 7, c = i & 127;
    ws[c*512 + 16 + r] = f2bf(W_dist[i]);
  } else if (i < 53248) {                // W_dmap [16][128]
    int j = i - 51200; int r = j >> 7, c = j & 127;
    ws[c*512 + r] = f2bf(W_dmap[j]);
  } else if (i < 55168) {                // W_dir [15][128]
    int j = i - 53248; int r = j >> 7, c = j & 127;
    ws[c*512 + 416 + r] = f2bf(W_dir[j]);
  } else if (i < 57088) {                // W_vec [15][128]
    int j = i - 55168; int r = j >> 7, c = j & 127;
    ws[c*512 + 431 + r] = f2bf(W_vec[j]);
  } else if (i < 58240) {                // W_rot [9][128]
    int j = i - 57088; int r = j >> 7, c = j & 127;
    ws[c*512 + 446 + r] = f2bf(W_rot[j]);
  } else if (i < 65536) {                // zero pad cols 455..511
    int j = i - 58240; int c = j / 57, r = j - 57*c;
    ws[c*512 + 455 + r] = 0;
  } else if (i < 98304) {                // W1 [128][256] -> W1T[n][k]
    int j = i - 65536; int k = j >> 8, nn = j & 255;
    ws[65536 + nn*128 + k] = f2bf(W1[j]);
  } else if (i < 131072) {               // W2 [256][128] -> W2T[n][k]
    int j = i - 98304; int k = j >> 7, nn = j & 127;
    ws[98304 + nn*256 + k] = f2bf(W2[j]);
  }
}

// ---- main: one block per residue, 256 threads (4 waves) ----
// LDS ~38.6 KB -> 4 blocks/CU (16 waves/CU)
__global__ __launch_bounds__(256) void fused_struct_kernel(
    const float* __restrict__ pos, const float* __restrict__ dmap,
    const float* __restrict__ mask, const float* __restrict__ W_relpos,
    const float* __restrict__ ln_scale, const float* __restrict__ ln_offset,
    const float* __restrict__ b1, const float* __restrict__ b2,
    const int* __restrict__ neighbours, const int* __restrict__ resi,
    const int* __restrict__ chain, const int* __restrict__ batch,
    const unsigned short* __restrict__ wsw, float* __restrict__ out)
{
  const int n = blockIdx.x;
  const int t = threadIdx.x;

  // reg1: F[48][264] bf16 == C[48][132] f32 == hb[48][264] bf16  (all 25344 B)
  __shared__ __align__(16) char reg1[48*FSTR*2];
  // reg2: pairb[48][136] bf16 (13056 B), aliased with feature scratch
  __shared__ __align__(16) char reg2[48*136*2];
  __shared__ int s_cls[48];

  unsigned short* s_F     = (unsigned short*)reg1;
  float*          s_C     = (float*)reg1;
  unsigned short* s_hb    = (unsigned short*)reg1;
  unsigned short* s_pairb = (unsigned short*)reg2;
  float* s_posnb = (float*)reg2;             // [48][16]
  float* s_Rnb   = (float*)(reg2 + 3072);    // [48][12]
  float* s_xall  = (float*)(reg2 + 5376);    // [26][48]: row0 dmap-x, rows1..25 dist-x
  float* s_posn  = (float*)(reg2 + 10368);   // 16
  float* s_Rn    = (float*)(reg2 + 10432);   // 12

  const unsigned short* wcatT = wsw;
  const unsigned short* w1T   = wsw + 65536;
  const unsigned short* w2T   = wsw + 98304;

  // ---------------- P1: neighbours, frames, mask, cls, dmap-x ----------------
  if (t < KNB) {
    const int k = t;
    const int nbraw = neighbours[n*KNB + k];
    int nb = nbraw; if (nb < 0) nb += N_RES;
    float p[15];
    const float* pp = pos + nb*15;
    #pragma unroll
    for (int d = 0; d < 15; ++d) { p[d] = pp[d]; s_posnb[k*16+d] = p[d]; }
    float R[9];
    frame_from_pos(p, R);
    #pragma unroll
    for (int d = 0; d < 9; ++d) s_Rnb[k*12+d] = R[d];

    float pm = mask[n] * mask[nb] * ((nbraw != -1) ? 1.0f : 0.0f);
    out[N_RES*KNB*PCH + n*KNB + k] = pm;

    int rel = resi[nb] - resi[n];
    rel = (rel < -32) ? -32 : (rel > 32 ? 32 : rel);
    rel += 32;
    bool same = (chain[nb] == chain[n]) && (batch[nb] == batch[n]);
    s_cls[k] = same ? rel : 65;

    // masked rows -> x=1e9 -> exp(-(1e9-b)^2) underflows to exact 0
    float xd = dmap[(long long)n*N_RES + nb] * INV_STEP;
    s_xall[k] = (pm > 0.0f) ? xd : 1e9f;
  } else if (t == 255) {
    float p[15];
    const float* pp = pos + n*15;
    #pragma unroll
    for (int d = 0; d < 15; ++d) { p[d] = pp[d]; s_posn[d] = p[d]; }
    float R[9];
    frame_from_pos(p, R);
    #pragma unroll
    for (int d = 0; d < 9; ++d) s_Rn[d] = R[d];
  }
  __syncthreads();

  // ---------------- P2a: all 25 atom-pair scaled distances ----------------
  for (int idx = t; idx < 1200; idx += 256) {
    int c = idx / 48, k = idx - 48*c;
    int a1 = c / 5, a2 = c - 5*a1;
    float dx = s_posn[a1*3+0] - s_posnb[k*16 + a2*3+0];
    float dy = s_posn[a1*3+1] - s_posnb[k*16 + a2*3+1];
    float dz = s_posn[a1*3+2] - s_posnb[k*16 + a2*3+2];
    float d2 = dx*dx + dy*dy + dz*dz;
    s_xall[48 + idx] = sqrtf(fmaxf(d2, 1e-12f)) * INV_STEP;
  }
  __syncthreads();

  // ---------------- P2b-A: stage F half-0 (cols 0..255 = dmap + dist c0..14) --
  // 3072 quad-tasks, 4 bins each, b64 writes
  for (int q = t; q < 3072; q += 256) {
    int cm = q >> 2, g = q & 3;
    int cp = cm / 48;                 // 0..15 ("chunk": 0=dmap, 1..15=dist c0..14)
    int m  = cm - 48*cp;
    float x = s_xall[cm];
    float d0 = x - (float)(4*g);
    float v0 = __expf(-(d0*d0));
    float d1 = d0 - 1.0f; float v1 = __expf(-(d1*d1));
    float d2 = d0 - 2.0f; float v2 = __expf(-(d2*d2));
    float d3 = d0 - 3.0f; float v3 = __expf(-(d3*d3));
    *(uint2*)&s_F[m*FSTR + cp*16 + 4*g] = make_uint2(pk2(v0, v1), pk2(v2, v3));
  }
  __syncthreads();

  // ---------------- GEMM1 half-0: K = 0..255 ----------------
  const int lane = t & 63;
  const int wv   = t >> 6;          // wave: output cols 32*wv..32*wv+31
  const int ln15 = lane & 15;
  const int quad = lane >> 4;

  f32x4 acc1[3][2] = {};
  #pragma unroll
  for (int kc = 0; kc < 8; ++kc) {
    bf16x8 a0 = *(const bf16x8*)(s_F + ( 0 + ln15)*FSTR + kc*32 + quad*8);
    bf16x8 a1 = *(const bf16x8*)(s_F + (16 + ln15)*FSTR + kc*32 + quad*8);
    bf16x8 a2 = *(const bf16x8*)(s_F + (32 + ln15)*FSTR + kc*32 + quad*8);
    bf16x8 b0 = *(const bf16x8*)(wcatT + (32*wv      + ln15)*512 + kc*32 + quad*8);
    bf16x8 b1v= *(const bf16x8*)(wcatT + (32*wv + 16 + ln15)*512 + kc*32 + quad*8);
    acc1[0][0] = __builtin_amdgcn_mfma_f32_16x16x32_bf16(a0, b0,  acc1[0][0], 0,0,0);
    acc1[1][0] = __builtin_amdgcn_mfma_f32_16x16x32_bf16(a1, b0,  acc1[1][0], 0,0,0);
    acc1[2][0] = __builtin_amdgcn_mfma_f32_16x16x32_bf16(a2, b0,  acc1[2][0], 0,0,0);
    acc1[0][1] = __builtin_amdgcn_mfma_f32_16x16x32_bf16(a0, b1v, acc1[0][1], 0,0,0);
    acc1[1][1] = __builtin_amdgcn_mfma_f32_16x16x32_bf16(a1, b1v, acc1[1][1], 0,0,0);
    acc1[2][1] = __builtin_amdgcn_mfma_f32_16x16x32_bf16(a2, b1v, acc1[2][1], 0,0,0);
  }
  __syncthreads();   // all half-0 F reads done

  // ---------------- P3: stage F half-1 (local cols 0..223 = dist c15..24 |
  //                      dir 160 | vec 175 | rot 190 | zero 199..223) ----------
  for (int q = t; q < 1920; q += 256) {     // dist c15..24
    int cm = q >> 2, g = q & 3;
    int cp = cm / 48;                 // 0..9
    int m  = cm - 48*cp;
    float x = s_xall[768 + cm];
    float d0 = x - (float)(4*g);
    float v0 = __expf(-(d0*d0));
    float d1 = d0 - 1.0f; float v1 = __expf(-(d1*d1));
    float d2 = d0 - 2.0f; float v2 = __expf(-(d2*d2));
    float d3 = d0 - 3.0f; float v3 = __expf(-(d3*d3));
    *(uint2*)&s_F[m*FSTR + cp*16 + 4*g] = make_uint2(pk2(v0, v1), pk2(v2, v3));
  }
  for (int idx = t; idx < 240; idx += 256) {  // dir + vec
    int k = idx / 5, a = idx - 5*k;
    float rx = s_posnb[k*16 + a*3+0] - s_posn[3];
    float ry = s_posnb[k*16 + a*3+1] - s_posn[4];
    float rz = s_posnb[k*16 + a*3+2] - s_posn[5];
    float l0 = s_Rn[0]*rx + s_Rn[3]*ry + s_Rn[6]*rz;
    float l1 = s_Rn[1]*rx + s_Rn[4]*ry + s_Rn[7]*rz;
    float l2 = s_Rn[2]*rx + s_Rn[5]*ry + s_Rn[8]*rz;
    s_F[k*FSTR + 175 + a*3+0] = f2bf(l0);       // vec (global k 431)
    s_F[k*FSTR + 175 + a*3+1] = f2bf(l1);
    s_F[k*FSTR + 175 + a*3+2] = f2bf(l2);
    float n2 = l0*l0 + l1*l1 + l2*l2;
    float inv = 1.0f / sqrtf(fmaxf(n2, 1e-6f));
    s_F[k*FSTR + 160 + a*3+0] = f2bf(l0*inv);   // dir (global k 416)
    s_F[k*FSTR + 160 + a*3+1] = f2bf(l1*inv);
    s_F[k*FSTR + 160 + a*3+2] = f2bf(l2*inv);
  }
  for (int idx = t; idx < 432; idx += 256) {  // rot (global k 446)
    int k = idx / 9, il = idx - 9*k;
    int i = il / 3, l = il - 3*i;
    float v = s_Rn[0+i]*s_Rnb[k*12 + 0+l]
            + s_Rn[3+i]*s_Rnb[k*12 + 3+l]
            + s_Rn[6+i]*s_Rnb[k*12 + 6+l];
    s_F[k*FSTR + 190 + il] = f2bf(v);
  }
  for (int idx = t; idx < 1200; idx += 256) { // zero pad (avoid stale NaN)
    int m = idx / 25, f = idx - 25*m;
    s_F[m*FSTR + 199 + f] = 0;
  }
  __syncthreads();

  // ---------------- GEMM1 half-1: K = 256..479 ----------------
  #pragma unroll
  for (int kc = 0; kc < 7; ++kc) {
    bf16x8 a0 = *(const bf16x8*)(s_F + ( 0 + ln15)*FSTR + kc*32 + quad*8);
    bf16x8 a1 = *(const bf16x8*)(s_F + (16 + ln15)*FSTR + kc*32 + quad*8);
    bf16x8 a2 = *(const bf16x8*)(s_F + (32 + ln15)*FSTR + kc*32 + quad*8);
    bf16x8 b0 = *(const bf16x8*)(wcatT + (32*wv      + ln15)*512 + 256 + kc*32 + quad*8);
    bf16x8 b1v= *(const bf16x8*)(wcatT + (32*wv + 16 + ln15)*512 + 256 + kc*32 + quad*8);
    acc1[0][0] = __builtin_amdgcn_mfma_f32_16x16x32_bf16(a0, b0,  acc1[0][0], 0,0,0);
    acc1[1][0] = __builtin_amdgcn_mfma_f32_16x16x32_bf16(a1, b0,  acc1[1][0], 0,0,0);
    acc1[2][0] = __builtin_amdgcn_mfma_f32_16x16x32_bf16(a2, b0,  acc1[2][0], 0,0,0);
    acc1[0][1] = __builtin_amdgcn_mfma_f32_16x16x32_bf16(a0, b1v, acc1[0][1], 0,0,0);
    acc1[1][1] = __builtin_amdgcn_mfma_f32_16x16x32_bf16(a1, b1v, acc1[1][1], 0,0,0);
    acc1[2][1] = __builtin_amdgcn_mfma_f32_16x16x32_bf16(a2, b1v, acc1[2][1], 0,0,0);
  }
  __syncthreads();   // all F reads done; reg1 -> C

  #pragma unroll
  for (int mt = 0; mt < 3; ++mt)
    #pragma unroll
    for (int nt = 0; nt < 2; ++nt) {
      int col = 32*wv + nt*16 + ln15;
      #pragma unroll
      for (int r = 0; r < 4; ++r)
        s_C[(mt*16 + quad*4 + r)*132 + col] = acc1[mt][nt][r];
    }
  __syncthreads();

  // ---------------- LN (+relpos row gather) -> pairb bf16 ----------------
  {
    const int c4 = t & 31;
    const int kg = t >> 5;
    float4 g  = *(const float4*)(ln_scale  + 4*c4);
    float4 o4 = *(const float4*)(ln_offset + 4*c4);
    #pragma unroll
    for (int j = 0; j < 6; ++j) {
      int k = kg*6 + j;
      float4 v = *(const float4*)&s_C[k*132 + 4*c4];
      float4 w = *(const float4*)(W_relpos + s_cls[k]*PCH + 4*c4);
      v.x += w.x; v.y += w.y; v.z += w.z; v.w += w.w;
      float s = v.x + v.y + v.z + v.w;
      float q = v.x*v.x + v.y*v.y + v.z*v.z + v.w*v.w;
      #pragma unroll
      for (int m = 1; m < 32; m <<= 1) {
        s += __shfl_xor(s, m);
        q += __shfl_xor(q, m);
      }
      float mu  = s * (1.0f/128.0f);
      float var = q * (1.0f/128.0f) - mu*mu;
      float inv = 1.0f / sqrtf(var + 1e-5f);
      unsigned int lo = pk2((v.x - mu)*inv*g.x + o4.x, (v.y - mu)*inv*g.y + o4.y);
      unsigned int hi = pk2((v.z - mu)*inv*g.z + o4.z, (v.w - mu)*inv*g.w + o4.w);
      *(uint2*)&s_pairb[k*136 + 4*c4] = make_uint2(lo, hi);
    }
  }
  __syncthreads();

  // ---------------- GEMM2: H[48][256] = pair @ W1, gelu -> hb ----------------
  f32x4 acc2[3][4] = {};
  #pragma unroll
  for (int kc = 0; kc < 4; ++kc) {
    bf16x8 a[3];
    #pragma unroll
    for (int mt = 0; mt < 3; ++mt)
      a[mt] = *(const bf16x8*)(s_pairb + (mt*16 + ln15)*136 + kc*32 + quad*8);
    bf16x8 b[4];
    #pragma unroll
    for (int nt = 0; nt < 4; ++nt)
      b[nt] = *(const bf16x8*)(w1T + (64*wv + nt*16 + ln15)*128 + kc*32 + quad*8);
    #pragma unroll
    for (int mt = 0; mt < 3; ++mt)
      #pragma unroll
      for (int nt = 0; nt < 4; ++nt)
        acc2[mt][nt] = __builtin_amdgcn_mfma_f32_16x16x32_bf16(a[mt], b[nt], acc2[mt][nt], 0,0,0);
  }
  #pragma unroll
  for (int nt = 0; nt < 4; ++nt) {
    int col = 64*wv + nt*16 + ln15;
    float bias = b1[col];
    #pragma unroll
    for (int mt = 0; mt < 3; ++mt)
      #pragma unroll
      for (int r = 0; r < 4; ++r)
        s_hb[(mt*16 + quad*4 + r)*FSTR + col] = f2bf(gelu_t(acc2[mt][nt][r] + bias));
  }
  __syncthreads();

  // ---------------- GEMM3: O[48][128] = hb @ W2 + b2 -> out ----------------
  f32x4 acc3[3][2] = {};
  #pragma unroll
  for (int kc = 0; kc < 8; ++kc) {
    bf16x8 a[3];
    #pragma unroll
    for (int mt = 0; mt < 3; ++mt)
      a[mt] = *(const bf16x8*)(s_hb + (mt*16 + ln15)*FSTR + kc*32 + quad*8);
    bf16x8 b0 = *(const bf16x8*)(w2T + (32*wv      + ln15)*256 + kc*32 + quad*8);
    bf16x8 b1v= *(const bf16x8*)(w2T + (32*wv + 16 + ln15)*256 + kc*32 + quad*8);
    #pragma unroll
    for (int mt = 0; mt < 3; ++mt) {
      acc3[mt][0] = __builtin_amdgcn_mfma_f32_16x16x32_bf16(a[mt], b0,  acc3[mt][0], 0,0,0);
      acc3[mt][1] = __builtin_amdgcn_mfma_f32_16x16x32_bf16(a[mt], b1v, acc3[mt][1], 0,0,0);
    }
  }
  #pragma unroll
  for (int nt = 0; nt < 2; ++nt) {
    int col = 32*wv + nt*16 + ln15;
    float bias = b2[col];
    #pragma unroll
    for (int mt = 0; mt < 3; ++mt)
      #pragma unroll
      for (int r = 0; r < 4; ++r)
        out[(n*KNB + mt*16 + quad*4 + r)*PCH + col] = acc3[mt][nt][r] + bias;
  }
}

extern "C" void kernel_launch(void* const* d_in, const int* in_sizes, int n_in,
                              void* d_out, int out_size, void* d_ws, size_t ws_size,
                              hipStream_t stream) {
  const float* pos       = (const float*)d_in[0];
  const float* dmap      = (const float*)d_in[1];
  const float* mask      = (const float*)d_in[2];
  const float* W_relpos  = (const float*)d_in[3];
  const float* W_dmap    = (const float*)d_in[4];
  const float* W_dist    = (const float*)d_in[5];
  const float* W_dir     = (const float*)d_in[6];
  const float* W_rot     = (const float*)d_in[7];
  const float* W_vec     = (const float*)d_in[8];
  const float* ln_scale  = (const float*)d_in[9];
  const float* ln_offset = (const float*)d_in[10];
  const float* W1        = (const float*)d_in[11];
  const float* b1        = (const float*)d_in[12];
  const float* W2        = (const float*)d_in[13];
  const float* b2        = (const float*)d_in[14];
  const int* neighbours  = (const int*)d_in[15];
  const int* resi        = (const int*)d_in[16];
  const int* chain       = (const int*)d_in[17];
  const int* batch       = (const int*)d_in[18];
  float* out = (float*)d_out;
  unsigned short* wsw = (unsigned short*)d_ws;

  hipLaunchKernelGGL(prep_weights, dim3(512), dim3(256), 0, stream,
                     W_dmap, W_dist, W_dir, W_vec, W_rot, W1, W2, wsw);
  hipLaunchKernelGGL(fused_struct_kernel, dim3(N_RES), dim3(256), 0, stream,
                     pos, dmap, mask, W_relpos, ln_scale, ln_offset, b1, b2,
                     neighbours, resi, chain, batch, wsw, out);
}

// Round 4
// 288.857 us; speedup vs baseline: 3.4281x; 1.1525x over previous
//
#include <hip/hip_runtime.h>
#include <hip/hip_bf16.h>

// N=4096, K=48, P=128, A=5, NBINS=16, RP=32
#define N_RES 4096
#define KNB   48
#define PCH   128
#define INV_STEP 0.727272727272727f
#define E2INV 0.13533528323661270f   // e^-2

typedef __bf16 bf16x8 __attribute__((ext_vector_type(8)));
typedef float  f32x4  __attribute__((ext_vector_type(4)));

// Fragment-linear bf16 weights (persist in the .so's device image; no d_ws use).
// wcat: K=544 (0..15 dmap | 16..415 dist | 416 dir | 431 vec | 446 rot |
//       455..520 relpos one-hot rows | 521..543 zero), layout [koct 68][col 128][8]
__device__ __align__(16) unsigned short g_wcat[68*128*8];
__device__ __align__(16) unsigned short g_w1[16*256*8];   // K=128, 256 hidden cols
__device__ __align__(16) unsigned short g_w2[32*128*8];   // K=256, 128 cols

__device__ __forceinline__ unsigned short f2bf(float f) {
  unsigned int u = __float_as_uint(f);
  return (unsigned short)((u + 0x7fffu + ((u >> 16) & 1u)) >> 16);
}
__device__ __forceinline__ unsigned int pk2(float a, float b) {
  __hip_bfloat162 h = __float22bfloat162_rn(make_float2(a, b));
  unsigned int u; __builtin_memcpy(&u, &h, 4); return u;
}
__device__ __forceinline__ float gelu_t(float x) {
  float u = 0.7978845608028654f * (x + 0.044715f * x * x * x);
  float a = fabsf(u);
  float e = __expf(-2.0f * a);
  float th = (1.0f - e) / (1.0f + e);
  th = (u < 0.0f) ? -th : th;
  return 0.5f * x * (1.0f + th);
}
__device__ __forceinline__ void frame_from_pos(const float* p, float* R) {
  float cax = p[3], cay = p[4], caz = p[5];
  float e1x = p[6]-cax, e1y = p[7]-cay, e1z = p[8]-caz;
  float i1 = 1.0f / sqrtf(fmaxf(e1x*e1x + e1y*e1y + e1z*e1z, 1e-6f));
  e1x *= i1; e1y *= i1; e1z *= i1;
  float vx = p[0]-cax, vy = p[1]-cay, vz = p[2]-caz;
  float dp = vx*e1x + vy*e1y + vz*e1z;
  float e2x = vx - dp*e1x, e2y = vy - dp*e1y, e2z = vz - dp*e1z;
  float i2 = 1.0f / sqrtf(fmaxf(e2x*e2x + e2y*e2y + e2z*e2z, 1e-6f));
  e2x *= i2; e2y *= i2; e2z *= i2;
  float e3x = e1y*e2z - e1z*e2y;
  float e3y = e1z*e2x - e1x*e2z;
  float e3z = e1x*e2y - e1y*e2x;
  R[0]=e1x; R[1]=e2x; R[2]=e3x;
  R[3]=e1y; R[4]=e2y; R[5]=e3y;
  R[6]=e1z; R[7]=e2z; R[8]=e3z;
}

// 16 RBF bins exp(-(x-b)^2) via two telescoping recurrences (up + down, merged
// with max to dodge underflow); writes two 16B frag-linear LDS stores per task.
__device__ __forceinline__ void stage_bins(unsigned short* sF, const float* s_xall,
                                           int xbase, int ntasks, int t) {
  for (int i = t; i < ntasks; i += 256) {
    int rloc = i / 48;
    int m = i - 48*rloc;
    float x = fminf(s_xall[(xbase + rloc)*48 + m], 25.0f);
    float u  = __expf(-x*x);
    float wu = __expf(2.0f*x - 1.0f);
    float xm = x - 15.0f;
    float d  = __expf(-xm*xm);
    float wd = __expf(-2.0f*xm - 1.0f);
    float bins[16];
    bins[0] = u;
    #pragma unroll
    for (int b = 1; b < 16; ++b) { u *= wu; wu *= E2INV; bins[b] = u; }
    bins[15] = fmaxf(bins[15], d);
    #pragma unroll
    for (int b = 14; b >= 0; --b) { d *= wd; wd *= E2INV; bins[b] = fmaxf(bins[b], d); }
    unsigned int p0 = pk2(bins[0], bins[1]),  p1 = pk2(bins[2], bins[3]);
    unsigned int p2 = pk2(bins[4], bins[5]),  p3 = pk2(bins[6], bins[7]);
    unsigned int p4 = pk2(bins[8], bins[9]),  p5 = pk2(bins[10], bins[11]);
    unsigned int p6 = pk2(bins[12], bins[13]),p7 = pk2(bins[14], bins[15]);
    int base = ((rloc*2)*48 + m)*8;          // (kc*4+quad) = 2*rloc
    *(uint4*)(sF + base)        = make_uint4(p0,p1,p2,p3);
    *(uint4*)(sF + base + 384)  = make_uint4(p4,p5,p6,p7);   // quad+1 => +48*8
  }
}

// ---- prep: fragment-linear bf16 weights, coalesced reads AND writes ----
__global__ __launch_bounds__(256) void prep_weights(
    const float* __restrict__ W_relpos, const float* __restrict__ W_dmap,
    const float* __restrict__ W_dist, const float* __restrict__ W_dir,
    const float* __restrict__ W_rot, const float* __restrict__ W_vec,
    const float* __restrict__ W1, const float* __restrict__ W2)
{
  int i = blockIdx.x*256 + threadIdx.x;
  unsigned short pk[8];
  if (i < 8704) {                       // wcat: oct = i>>7 (68), col = i&127
    int oct = i >> 7, col = i & 127;
    #pragma unroll
    for (int j = 0; j < 8; ++j) {
      int k = oct*8 + j;
      float v;
      if      (k < 16)  v = W_dmap[k*128 + col];
      else if (k < 416) v = W_dist[(k-16)*128 + col];
      else if (k < 431) v = W_dir[(k-416)*128 + col];
      else if (k < 446) v = W_vec[(k-431)*128 + col];
      else if (k < 455) v = W_rot[(k-446)*128 + col];
      else if (k < 521) v = W_relpos[(k-455)*128 + col];
      else              v = 0.0f;
      pk[j] = f2bf(v);
    }
    *(uint4*)(g_wcat + i*8) = *(uint4*)pk;
  } else if (i < 12800) {               // w1: oct(16) x col(256)
    int j2 = i - 8704;
    int oct = j2 >> 8, col = j2 & 255;
    #pragma unroll
    for (int j = 0; j < 8; ++j) pk[j] = f2bf(W1[(oct*8+j)*256 + col]);
    *(uint4*)(g_w1 + j2*8) = *(uint4*)pk;
  } else if (i < 16896) {               // w2: oct(32) x col(128)
    int j3 = i - 12800;
    int oct = j3 >> 7, col = j3 & 127;
    #pragma unroll
    for (int j = 0; j < 8; ++j) pk[j] = f2bf(W2[(oct*8+j)*128 + col]);
    *(uint4*)(g_w2 + j3*8) = *(uint4*)pk;
  }
}

#define MFMA6(A0,A1,A2,B0,B1,ACC) \
  ACC[0][0] = __builtin_amdgcn_mfma_f32_16x16x32_bf16(A0, B0, ACC[0][0], 0,0,0); \
  ACC[1][0] = __builtin_amdgcn_mfma_f32_16x16x32_bf16(A1, B0, ACC[1][0], 0,0,0); \
  ACC[2][0] = __builtin_amdgcn_mfma_f32_16x16x32_bf16(A2, B0, ACC[2][0], 0,0,0); \
  ACC[0][1] = __builtin_amdgcn_mfma_f32_16x16x32_bf16(A0, B1, ACC[0][1], 0,0,0); \
  ACC[1][1] = __builtin_amdgcn_mfma_f32_16x16x32_bf16(A1, B1, ACC[1][1], 0,0,0); \
  ACC[2][1] = __builtin_amdgcn_mfma_f32_16x16x32_bf16(A2, B1, ACC[2][1], 0,0,0);

// ---- main: one block per residue, 256 threads; LDS ~25 KB -> 5 blocks/CU ----
__global__ __launch_bounds__(256, 5) void fused_struct_kernel(
    const float* __restrict__ pos, const float* __restrict__ dmap,
    const float* __restrict__ mask, const float* __restrict__ ln_scale,
    const float* __restrict__ ln_offset, const float* __restrict__ b1,
    const float* __restrict__ b2, const int* __restrict__ neighbours,
    const int* __restrict__ resi, const int* __restrict__ chain,
    const int* __restrict__ batch, float* __restrict__ out)
{
  const int n = blockIdx.x;
  const int t = threadIdx.x;
  const int lane = t & 63;
  const int wv   = t >> 6;
  const int ln15 = lane & 15;
  const int quad = lane >> 4;

  __shared__ __align__(16) char regF[12288];   // F stage / hb half (frag-linear bf16)
  __shared__ __align__(16) char regP[12288];   // scratch -> pairb (frag-linear bf16)
  __shared__ __align__(16) float2 s_stats[48];

  unsigned short* sF    = (unsigned short*)regF;
  unsigned short* sPair = (unsigned short*)regP;
  float*  s_posnb = (float*)regP;              // [48][16]
  float*  s_Rnb   = (float*)(regP + 3072);     // [48][12]
  float*  s_xall  = (float*)(regP + 5376);     // [26][48] scaled dists (row0=dmap)
  float*  s_posn  = (float*)(regP + 10368);    // 16
  float*  s_Rn    = (float*)(regP + 10432);    // 12
  int*    s_cls   = (int*)  (regP + 10496);    // 48
  float2* s_part  = (float2*)(regP + 10752);   // [4][48]

  // ---------------- P1 ----------------
  if (t < KNB) {
    const int k = t;
    const int nbraw = neighbours[n*KNB + k];
    int nb = nbraw; if (nb < 0) nb += N_RES;
    float p[15];
    const float* pp = pos + nb*15;
    #pragma unroll
    for (int d = 0; d < 15; ++d) { p[d] = pp[d]; s_posnb[k*16+d] = p[d]; }
    float R[9];
    frame_from_pos(p, R);
    #pragma unroll
    for (int d = 0; d < 9; ++d) s_Rnb[k*12+d] = R[d];

    float pm = mask[n] * mask[nb] * ((nbraw != -1) ? 1.0f : 0.0f);
    out[N_RES*KNB*PCH + n*KNB + k] = pm;

    int rel = resi[nb] - resi[n];
    rel = (rel < -32) ? -32 : (rel > 32 ? 32 : rel);
    rel += 32;
    bool same = (chain[nb] == chain[n]) && (batch[nb] == batch[n]);
    s_cls[k] = same ? rel : 65;

    float xd = dmap[(long long)n*N_RES + nb] * INV_STEP;
    s_xall[k] = (pm > 0.0f) ? xd : 30.0f;     // 30 -> all bins underflow to 0
  } else if (t == 255) {
    float p[15];
    const float* pp = pos + n*15;
    #pragma unroll
    for (int d = 0; d < 15; ++d) { p[d] = pp[d]; s_posn[d] = p[d]; }
    float R[9];
    frame_from_pos(p, R);
    #pragma unroll
    for (int d = 0; d < 9; ++d) s_Rn[d] = R[d];
  }
  __syncthreads();

  // ---------------- P2: 25 atom-pair scaled distances ----------------
  for (int idx = t; idx < 1200; idx += 256) {
    int c = idx / 48, k = idx - 48*c;
    int a1 = c / 5, a2 = c - 5*a1;
    float dx = s_posn[a1*3+0] - s_posnb[k*16 + a2*3+0];
    float dy = s_posn[a1*3+1] - s_posnb[k*16 + a2*3+1];
    float dz = s_posn[a1*3+2] - s_posnb[k*16 + a2*3+2];
    float d2 = dx*dx + dy*dy + dz*dz;
    s_xall[48 + idx] = sqrtf(fmaxf(d2, 1e-12f)) * INV_STEP;
  }
  __syncthreads();

  // ---------------- GEMM1 over 4x128 + 1x32 K-stages ----------------
  f32x4 acc1[3][2] = {};

  #pragma unroll 1
  for (int st = 0; st < 3; ++st) {
    stage_bins(sF, s_xall, st*8, 384, t);
    __syncthreads();
    #pragma unroll
    for (int kc = 0; kc < 4; ++kc) {
      const unsigned short* ab = sF + ((kc*4 + quad)*48 + ln15)*8;
      bf16x8 a0 = *(const bf16x8*)(ab);
      bf16x8 a1 = *(const bf16x8*)(ab + 128);
      bf16x8 a2 = *(const bf16x8*)(ab + 256);
      const unsigned short* bb = g_wcat + (((st*4+kc)*4 + quad)*128 + 32*wv + ln15)*8;
      bf16x8 b0 = *(const bf16x8*)(bb);
      bf16x8 b1v= *(const bf16x8*)(bb + 128);
      MFMA6(a0,a1,a2,b0,b1v,acc1)
    }
    __syncthreads();
  }

  // stage 3: k 384..511 = dist c23,c24 | dir | vec | rot | relpos(cls<=56)
  for (int i = t; i < 768; i += 256) ((uint4*)sF)[i] = make_uint4(0,0,0,0);
  __syncthreads();
  stage_bins(sF, s_xall, 24, 96, t);
  for (int idx = t; idx < 240; idx += 256) {   // dir (l=32..46) + vec (l=47..61)
    int k = idx / 5, a = idx - 5*k;
    float rx = s_posnb[k*16 + a*3+0] - s_posn[3];
    float ry = s_posnb[k*16 + a*3+1] - s_posn[4];
    float rz = s_posnb[k*16 + a*3+2] - s_posn[5];
    float l0 = s_Rn[0]*rx + s_Rn[3]*ry + s_Rn[6]*rz;
    float l1 = s_Rn[1]*rx + s_Rn[4]*ry + s_Rn[7]*rz;
    float l2 = s_Rn[2]*rx + s_Rn[5]*ry + s_Rn[8]*rz;
    float inv = 1.0f / sqrtf(fmaxf(l0*l0 + l1*l1 + l2*l2, 1e-6f));
    int lv = 47 + a*3, ld = 32 + a*3;
    sF[((lv>>3)*48 + k)*8 + (lv&7)] = f2bf(l0);
    lv++; sF[((lv>>3)*48 + k)*8 + (lv&7)] = f2bf(l1);
    lv++; sF[((lv>>3)*48 + k)*8 + (lv&7)] = f2bf(l2);
    sF[((ld>>3)*48 + k)*8 + (ld&7)] = f2bf(l0*inv);
    ld++; sF[((ld>>3)*48 + k)*8 + (ld&7)] = f2bf(l1*inv);
    ld++; sF[((ld>>3)*48 + k)*8 + (ld&7)] = f2bf(l2*inv);
  }
  for (int idx = t; idx < 432; idx += 256) {   // rot (l=62..70)
    int k = idx / 9, il = idx - 9*k;
    int i2 = il / 3, l2c = il - 3*i2;
    float v = s_Rn[0+i2]*s_Rnb[k*12 + 0+l2c]
            + s_Rn[3+i2]*s_Rnb[k*12 + 3+l2c]
            + s_Rn[6+i2]*s_Rnb[k*12 + 6+l2c];
    int l = 62 + il;
    sF[((l>>3)*48 + k)*8 + (l&7)] = f2bf(v);
  }
  if (t < 48) {                                // relpos one-hot, low part
    int c = s_cls[t];
    if (c <= 56) { int l = 71 + c; sF[((l>>3)*48 + t)*8 + (l&7)] = 0x3F80; }
  }
  __syncthreads();
  #pragma unroll
  for (int kc = 0; kc < 4; ++kc) {
    const unsigned short* ab = sF + ((kc*4 + quad)*48 + ln15)*8;
    bf16x8 a0 = *(const bf16x8*)(ab);
    bf16x8 a1 = *(const bf16x8*)(ab + 128);
    bf16x8 a2 = *(const bf16x8*)(ab + 256);
    const unsigned short* bb = g_wcat + (((12+kc)*4 + quad)*128 + 32*wv + ln15)*8;
    bf16x8 b0 = *(const bf16x8*)(bb);
    bf16x8 b1v= *(const bf16x8*)(bb + 128);
    MFMA6(a0,a1,a2,b0,b1v,acc1)
  }
  __syncthreads();

  // stage 4: k 512..543 = relpos cls>=57 + pad (1 kc chunk)
  for (int i = t; i < 192; i += 256) ((uint4*)sF)[i] = make_uint4(0,0,0,0);
  __syncthreads();
  if (t < 48) {
    int c = s_cls[t];
    if (c >= 57) { int l = c - 57; sF[((l>>3)*48 + t)*8 + (l&7)] = 0x3F80; }
  }
  __syncthreads();
  {
    const unsigned short* ab = sF + (quad*48 + ln15)*8;
    bf16x8 a0 = *(const bf16x8*)(ab);
    bf16x8 a1 = *(const bf16x8*)(ab + 128);
    bf16x8 a2 = *(const bf16x8*)(ab + 256);
    const unsigned short* bb = g_wcat + ((64 + quad)*128 + 32*wv + ln15)*8;  // oct 64..67
    bf16x8 b0 = *(const bf16x8*)(bb);
    bf16x8 b1v= *(const bf16x8*)(bb + 128);
    MFMA6(a0,a1,a2,b0,b1v,acc1)
  }

  // ---------------- LayerNorm in registers ----------------
  #pragma unroll
  for (int mt = 0; mt < 3; ++mt)
    #pragma unroll
    for (int r = 0; r < 4; ++r) {
      float a0v = acc1[mt][0][r], a1v = acc1[mt][1][r];
      float sv = a0v + a1v;
      float qv = a0v*a0v + a1v*a1v;
      #pragma unroll
      for (int msk = 1; msk < 16; msk <<= 1) {
        sv += __shfl_xor(sv, msk);
        qv += __shfl_xor(qv, msk);
      }
      if (ln15 == 0) s_part[wv*48 + mt*16 + quad*4 + r] = make_float2(sv, qv);
    }
  __syncthreads();
  if (t < 48) {
    float S = 0.0f, Q = 0.0f;
    #pragma unroll
    for (int w = 0; w < 4; ++w) { float2 p = s_part[w*48 + t]; S += p.x; Q += p.y; }
    float mu = S * (1.0f/128.0f);
    float var = Q * (1.0f/128.0f) - mu*mu;
    s_stats[t] = make_float2(mu, 1.0f / sqrtf(var + 1e-5f));
  }
  __syncthreads();
  {
    int c0 = 32*wv + ln15;
    float gg0 = ln_scale[c0],  gg1 = ln_scale[c0+16];
    float oo0 = ln_offset[c0], oo1 = ln_offset[c0+16];
    #pragma unroll
    for (int mt = 0; mt < 3; ++mt)
      #pragma unroll
      for (int r = 0; r < 4; ++r) {
        int row = mt*16 + quad*4 + r;
        float2 stt = s_stats[row];
        float v0 = (acc1[mt][0][r] - stt.x)*stt.y*gg0 + oo0;
        float v1 = (acc1[mt][1][r] - stt.x)*stt.y*gg1 + oo1;
        sPair[((c0>>3)*48 + row)*8 + (c0&7)] = f2bf(v0);
        int c1 = c0 + 16;
        sPair[((c1>>3)*48 + row)*8 + (c1&7)] = f2bf(v1);
      }
  }
  __syncthreads();

  // ---------------- MLP: two hidden halves of 128 ----------------
  f32x4 acc3[3][2] = {};
  #pragma unroll 1
  for (int half = 0; half < 2; ++half) {
    f32x4 acc2[3][2] = {};
    #pragma unroll
    for (int kc = 0; kc < 4; ++kc) {
      const unsigned short* ab = sPair + ((kc*4 + quad)*48 + ln15)*8;
      bf16x8 a0 = *(const bf16x8*)(ab);
      bf16x8 a1 = *(const bf16x8*)(ab + 128);
      bf16x8 a2 = *(const bf16x8*)(ab + 256);
      const unsigned short* bb = g_w1 + ((kc*4 + quad)*256 + half*128 + 32*wv + ln15)*8;
      bf16x8 b0 = *(const bf16x8*)(bb);
      bf16x8 b1v= *(const bf16x8*)(bb + 128);
      MFMA6(a0,a1,a2,b0,b1v,acc2)
    }
    __syncthreads();   // previous readers of sF/hb are done
    {
      int hc = half*128 + 32*wv + ln15;
      float bb0 = b1[hc], bb1 = b1[hc+16];
      int l0 = 32*wv + ln15, l1 = l0 + 16;
      #pragma unroll
      for (int mt = 0; mt < 3; ++mt)
        #pragma unroll
        for (int r = 0; r < 4; ++r) {
          int row = mt*16 + quad*4 + r;
          sF[((l0>>3)*48 + row)*8 + (l0&7)] = f2bf(gelu_t(acc2[mt][0][r] + bb0));
          sF[((l1>>3)*48 + row)*8 + (l1&7)] = f2bf(gelu_t(acc2[mt][1][r] + bb1));
        }
    }
    __syncthreads();
    #pragma unroll
    for (int kc = 0; kc < 4; ++kc) {
      const unsigned short* ab = sF + ((kc*4 + quad)*48 + ln15)*8;
      bf16x8 a0 = *(const bf16x8*)(ab);
      bf16x8 a1 = *(const bf16x8*)(ab + 128);
      bf16x8 a2 = *(const bf16x8*)(ab + 256);
      const unsigned short* bb = g_w2 + (((half*4 + kc)*4 + quad)*128 + 32*wv + ln15)*8;
      bf16x8 b0 = *(const bf16x8*)(bb);
      bf16x8 b1v= *(const bf16x8*)(bb + 128);
      MFMA6(a0,a1,a2,b0,b1v,acc3)
    }
  }

  // ---------------- epilogue: out = acc3 + b2 ----------------
  {
    int c0 = 32*wv + ln15;
    float bo0 = b2[c0], bo1 = b2[c0+16];
    #pragma unroll
    for (int mt = 0; mt < 3; ++mt)
      #pragma unroll
      for (int r = 0; r < 4; ++r) {
        int row = mt*16 + quad*4 + r;
        out[(n*KNB + row)*PCH + c0]      = acc3[mt][0][r] + bo0;
        out[(n*KNB + row)*PCH + c0 + 16] = acc3[mt][1][r] + bo1;
      }
  }
}

extern "C" void kernel_launch(void* const* d_in, const int* in_sizes, int n_in,
                              void* d_out, int out_size, void* d_ws, size_t ws_size,
                              hipStream_t stream) {
  const float* pos       = (const float*)d_in[0];
  const float* dmap      = (const float*)d_in[1];
  const float* mask      = (const float*)d_in[2];
  const float* W_relpos  = (const float*)d_in[3];
  const float* W_dmap    = (const float*)d_in[4];
  const float* W_dist    = (const float*)d_in[5];
  const float* W_dir     = (const float*)d_in[6];
  const float* W_rot     = (const float*)d_in[7];
  const float* W_vec     = (const float*)d_in[8];
  const float* ln_scale  = (const float*)d_in[9];
  const float* ln_offset = (const float*)d_in[10];
  const float* W1        = (const float*)d_in[11];
  const float* b1        = (const float*)d_in[12];
  const float* W2        = (const float*)d_in[13];
  const float* b2        = (const float*)d_in[14];
  const int* neighbours  = (const int*)d_in[15];
  const int* resi        = (const int*)d_in[16];
  const int* chain       = (const int*)d_in[17];
  const int* batch       = (const int*)d_in[18];
  float* out = (float*)d_out;

  hipLaunchKernelGGL(prep_weights, dim3(66), dim3(256), 0, stream,
                     W_relpos, W_dmap, W_dist, W_dir, W_rot, W_vec, W1, W2);
  hipLaunchKernelGGL(fused_struct_kernel, dim3(N_RES), dim3(256), 0, stream,
                     pos, dmap, mask, ln_scale, ln_offset, b1, b2,
                     neighbours, resi, chain, batch, out);
}